// Round 2
// baseline (883.307 us; speedup 1.0000x reference)
//
#include <hip/hip_runtime.h>
#include <math.h>

#define LN2PI 1.83787706640934548356f

// ---------------------------------------------------------------------------
// 4x4 matmul V = W @ M   (row-major, m = r*4+c)
// ---------------------------------------------------------------------------
__device__ __forceinline__ void compute_V(const float* __restrict__ Wm,
                                          const float* __restrict__ Mm,
                                          float* V) {
    float w[16], m[16];
    #pragma unroll
    for (int k = 0; k < 16; ++k) { w[k] = Wm[k]; m[k] = Mm[k]; }
    #pragma unroll
    for (int r = 0; r < 4; ++r) {
        #pragma unroll
        for (int cc = 0; cc < 4; ++cc) {
            float s = w[r*4+0] * m[0*4+cc];
            s = fmaf(w[r*4+1], m[1*4+cc], s);
            s = fmaf(w[r*4+2], m[2*4+cc], s);
            s = fmaf(w[r*4+3], m[3*4+cc], s);
            V[r*4+cc] = s;
        }
    }
}

// ---------------------------------------------------------------------------
// stem: conv 5x5 stride 2 valid + bias + relu : (16,2,32,32) -> (16,32,14,14)
// ---------------------------------------------------------------------------
__global__ void k_stem(const float* __restrict__ x, const float* __restrict__ w,
                       const float* __restrict__ bias, float* __restrict__ fea) {
    int idx = blockIdx.x * blockDim.x + threadIdx.x;
    if (idx >= 16*32*14*14) return;
    int ox = idx % 14, oy = (idx/14) % 14, oc = (idx/196) % 32, b = idx/(196*32);
    float s = bias[oc];
    const float* xb = x + b*2*32*32;
    const float* wc = w + oc*2*25;
    #pragma unroll
    for (int ic = 0; ic < 2; ++ic)
        #pragma unroll
        for (int ky = 0; ky < 5; ++ky)
            #pragma unroll
            for (int kx = 0; kx < 5; ++kx)
                s = fmaf(xb[ic*1024 + (oy*2+ky)*32 + (ox*2+kx)],
                         wc[ic*25 + ky*5 + kx], s);
    fea[idx] = fmaxf(s, 0.f);
}

// ---------------------------------------------------------------------------
// primary caps
// ---------------------------------------------------------------------------
__global__ void k_primary(const float* __restrict__ fea,
                          const float* __restrict__ pw, const float* __restrict__ pb,
                          const float* __restrict__ aw, const float* __restrict__ ab,
                          float* __restrict__ M, float* __restrict__ a) {
    int idx = blockIdx.x * blockDim.x + threadIdx.x;
    if (idx >= 16*544*196) return;
    int hw = idx % 196, o = (idx/196) % 544, b = idx/(196*544);
    const float* f = fea + b*32*196 + hw;
    if (o < 512) {
        float s = pb[o];
        #pragma unroll
        for (int c = 0; c < 32; ++c) s = fmaf(f[c*196], pw[o*32+c], s);
        M[(b*512+o)*196 + hw] = s;
    } else {
        int oo = o - 512;
        float s = ab[oo];
        #pragma unroll
        for (int c = 0; c < 32; ++c) s = fmaf(f[c*196], aw[oo*32+c], s);
        a[(b*32+oo)*196 + hw] = 1.f/(1.f + expf(-s));
    }
}

// ---------------------------------------------------------------------------
// patch extraction, p-major: aP[(b*P+p)*ni + i], Mp[((b*P+p)*ni + i)*16]
// ---------------------------------------------------------------------------
__global__ void k_patch(const float* __restrict__ a_in, const float* __restrict__ M_in,
                        float* __restrict__ aP, float* __restrict__ Mp,
                        int B, int K, int stride, int h, int w, int oh, int ow) {
    int P = oh*ow, KK = K*K, ni = B*KK;
    int idx = blockIdx.x * blockDim.x + threadIdx.x;
    if (idx >= 16*ni*P) return;
    int i = idx % ni, p = (idx/ni) % P, b = idx/(ni*P);
    int Bi = i / KK, kk = i % KK, ki = kk / K, kj = kk % K;
    int py = p / ow, px = p % ow;
    int src = (py*stride + ki)*w + (px*stride + kj);
    int hw = h*w;
    aP[idx] = a_in[(b*B + Bi)*hw + src];
    const float* Ms = M_in + (size_t)((b*B + Bi)*16)*hw + src;
    float* Md = Mp + (size_t)idx*16;
    #pragma unroll
    for (int m = 0; m < 16; ++m) Md[m] = Ms[m*hw];
}

// ---------------------------------------------------------------------------
// W transpose: Wt[(c*NI+i)*16+m] = W[(i*C+c)*16+m]
// ---------------------------------------------------------------------------
__global__ void k_wt(const float* __restrict__ W, float* __restrict__ Wt,
                     int NI, int C) {
    int idx = blockIdx.x * blockDim.x + threadIdx.x;
    if (idx >= NI*C*16) return;
    int m = idx % 16, i = (idx/16) % NI, c = idx/(16*NI);
    Wt[idx] = W[(i*C + c)*16 + m];
}

// ---------------------------------------------------------------------------
// EM stats: one wave per (b,j). Recomputes R[i][j] on the fly from (mxs,ism)
// plus the PREVIOUS iteration's stats for its own j (held in registers).
// blockIdx = c*(16*P) + (bb*P + p)  so all c-blocks of a (b,p) slice share an XCD.
// ---------------------------------------------------------------------------
template<int NI, int NJ, int P, int C>
__global__ __launch_bounds__(64) void k_stats(
    const float* __restrict__ aP, const float* __restrict__ Mp,
    const float* __restrict__ Wt,
    const float* __restrict__ mxs, const float* __restrict__ ism,
    const float* __restrict__ beta_a, const float* __restrict__ beta_u,
    float* __restrict__ miu, float* __restrict__ isig, float* __restrict__ lss,
    float* __restrict__ aout, float* __restrict__ a_fin, float* __restrict__ M_fin,
    int t, float lam, int final_flag)
{
    constexpr int NIT = (NI + 63) / 64;
    int g  = blockIdx.x % (16*P);
    int c  = blockIdx.x / (16*P);
    int bb = g / P, p = g % P;
    int j  = c*P + p;
    int lane = threadIdx.x;

    // previous-iteration stats for our j (uniform across wave)
    float muO[16], isO[16], lssO = 0.f, aoO = 0.f;
    if (t > 0) {
        const float* mo = miu  + (size_t)(bb*NJ + j)*16;
        const float* io = isig + (size_t)(bb*NJ + j)*16;
        #pragma unroll
        for (int m = 0; m < 16; ++m) { muO[m] = mo[m]; isO[m] = io[m]; }
        lssO = lss[bb*NJ + j];
        aoO  = aout[bb*NJ + j];
    }

    const float* aPb = aP + (size_t)(bb*P + p)*NI;
    const float* Mpb = Mp + (size_t)(bb*P + p)*NI*16;
    const float* Wtc = Wt + (size_t)c*NI*16;
    const float* mxb = mxs + (size_t)bb*NI;
    const float* imb = ism + (size_t)bb*NI;

    float wc[NIT];
    float accw = 0.f, accm[16];
    #pragma unroll
    for (int m = 0; m < 16; ++m) accm[m] = 0.f;

    #pragma unroll
    for (int it = 0; it < NIT; ++it) {
        int i = lane + it*64;
        wc[it] = 0.f;
        if ((NI % 64 == 0) || (i < NI)) {
            float V[16];
            compute_V(Wtc + i*16, Mpb + (size_t)i*16, V);
            float r;
            if (t == 0) {
                r = 1.f / NJ;
            } else {
                float q = 0.f;
                #pragma unroll
                for (int m = 0; m < 16; ++m) {
                    float d = V[m] - muO[m];
                    q = fmaf(d*d, isO[m], q);
                }
                float logp = -0.5f * (16.f*LN2PI + lssO + q);
                r = expf(aoO*logp - mxb[i]) * imb[i];
            }
            float wgt = r * aPb[i];
            wc[it] = wgt;
            accw += wgt;
            #pragma unroll
            for (int m = 0; m < 16; ++m) accm[m] = fmaf(wgt, V[m], accm[m]);
        }
    }

    for (int off = 1; off < 64; off <<= 1) {
        accw += __shfl_xor(accw, off);
        #pragma unroll
        for (int m = 0; m < 16; ++m) accm[m] += __shfl_xor(accm[m], off);
    }
    float coeff = fmaxf(accw, 1e-8f);
    float mu[16];
    #pragma unroll
    for (int m = 0; m < 16; ++m) mu[m] = accm[m] / coeff;

    // pass 2: recompute V (no register cache -> no scratch spill)
    float accs[16];
    #pragma unroll
    for (int m = 0; m < 16; ++m) accs[m] = 0.f;
    #pragma unroll
    for (int it = 0; it < NIT; ++it) {
        int i = lane + it*64;
        if ((NI % 64 == 0) || (i < NI)) {
            float V[16];
            compute_V(Wtc + i*16, Mpb + (size_t)i*16, V);
            #pragma unroll
            for (int m = 0; m < 16; ++m) {
                float d = V[m] - mu[m];
                accs[m] = fmaf(wc[it], d*d, accs[m]);
            }
        }
    }
    for (int off = 1; off < 64; off <<= 1) {
        #pragma unroll
        for (int m = 0; m < 16; ++m) accs[m] += __shfl_xor(accs[m], off);
    }

    float lsum = 0.f, isv[16];
    #pragma unroll
    for (int m = 0; m < 16; ++m) {
        float s = fmaxf(accs[m] / coeff, 1e-8f);
        lsum += logf(s);
        isv[m] = 1.f / s;
    }
    float ba = beta_a[j % C], bu = beta_u[j % C];
    float ao = 1.f/(1.f + expf(-(lam * (ba - (16.f*bu + 0.5f*lsum) * coeff))));

    if (lane == 0) {
        float* mo = miu  + (size_t)(bb*NJ + j)*16;
        float* io = isig + (size_t)(bb*NJ + j)*16;
        #pragma unroll
        for (int m = 0; m < 16; ++m) { mo[m] = mu[m]; io[m] = isv[m]; }
        lss[bb*NJ + j] = lsum;
        aout[bb*NJ + j] = ao;
        if (final_flag) {
            a_fin[bb*NJ + j] = ao;
            #pragma unroll
            for (int m = 0; m < 16; ++m)
                M_fin[(size_t)(bb*16 + m)*NJ + j] = mu[m];  // faithful transpose scramble
        }
    }
}

// ---------------------------------------------------------------------------
// softmax reduction: per (b,i) store max_j(sv) and 1/sum_j exp(sv-max).
// 4 waves per block = 4 consecutive i.
// ---------------------------------------------------------------------------
template<int NI, int NJ, int P, int C>
__global__ __launch_bounds__(256) void k_Rred(
    const float* __restrict__ Mp, const float* __restrict__ W,
    const float* __restrict__ miu, const float* __restrict__ isig,
    const float* __restrict__ lss, const float* __restrict__ aout,
    float* __restrict__ mxs, float* __restrict__ ism)
{
    constexpr int NJL = (NJ + 63) / 64;
    int bi = blockIdx.x % (NI/4);
    int bb = blockIdx.x / (NI/4);
    int wave = threadIdx.x >> 6, lane = threadIdx.x & 63;
    int i = bi*4 + wave;

    const float* Wi  = W  + (size_t)i*C*16;                 // uniform per wave
    const float* Mpb = Mp + ((size_t)(bb*P)*NI + i)*16;     // + p*NI*16 per p
    float mx = -3.0e38f, sm = 0.f;

    #pragma unroll
    for (int k = 0; k < NJL; ++k) {
        int j = lane + k*64;
        if ((NJ % 64 == 0) || (j < NJ)) {
            int cc = j / P, p = j % P;
            float V[16];
            compute_V(Wi + cc*16, Mpb + (size_t)p*NI*16, V);
            const float* mo = miu  + (size_t)(bb*NJ + j)*16;
            const float* io = isig + (size_t)(bb*NJ + j)*16;
            float q = 0.f;
            #pragma unroll
            for (int m = 0; m < 16; ++m) {
                float d = V[m] - mo[m];
                q = fmaf(d*d, io[m], q);
            }
            float logp = -0.5f * (16.f*LN2PI + lss[bb*NJ + j] + q);
            float sv = aout[bb*NJ + j] * logp;
            if (sv > mx) { sm = sm * expf(mx - sv) + 1.f; mx = sv; }
            else         { sm += expf(sv - mx); }
        }
    }
    // wave-level log-sum-exp merge
    for (int off = 1; off < 64; off <<= 1) {
        float mo_ = __shfl_xor(mx, off);
        float so_ = __shfl_xor(sm, off);
        float M = fmaxf(mx, mo_);
        sm = sm * expf(mx - M) + so_ * expf(mo_ - M);
        mx = M;
    }
    if (lane == 0) {
        mxs[bb*NI + i] = mx;
        ism[bb*NI + i] = 1.f / sm;
    }
}

// ---------------------------------------------------------------------------
// layer 4 fused: patch + 3 EM iterations, one block per batch element.
// share=1 (W4 per (Bi,c)), coord=1. NI=512, NJ=C=5, P=1, KK=16.
// ---------------------------------------------------------------------------
__global__ __launch_bounds__(256) void k_layer4(
    const float* __restrict__ a3, const float* __restrict__ M3,
    const float* __restrict__ W4, const float* __restrict__ ba4,
    const float* __restrict__ bu4, float* __restrict__ out)
{
    __shared__ float sM[512*16];    // 32KB
    __shared__ float sA[512];
    __shared__ float sW[32*5*16];   // 10KB
    __shared__ float sR[512*5];     // 10KB
    __shared__ float red[4][17];
    __shared__ float sStat[5][34];  // mu[16], isig[16], lsum, ao

    int b = blockIdx.x, tid = threadIdx.x;
    int lane = tid & 63, wave = tid >> 6;

    for (int k = tid; k < 512*16; k += 256) {
        int i = k >> 4, m = k & 15;
        sM[k] = M3[b*8192 + (i & ~15)*16 + m*16 + (i & 15)];
    }
    for (int k = tid; k < 512; k += 256)  sA[k] = a3[b*512 + k];
    for (int k = tid; k < 2560; k += 256) sW[k] = W4[k];
    for (int k = tid; k < 2560; k += 256) sR[k] = 0.2f;
    __syncthreads();

    const float lams[3] = {5.0e-4f, 9.75e-4f, 1.426250e-3f};

    for (int t = 0; t < 3; ++t) {
        float lam = lams[t];
        for (int j = 0; j < 5; ++j) {
            float cw = 0.f, cm[16];
            float Vr[2][16], wr[2];
            #pragma unroll
            for (int m = 0; m < 16; ++m) cm[m] = 0.f;
            #pragma unroll
            for (int u = 0; u < 2; ++u) {
                int i = tid + u*256;
                float wgt = sR[i*5 + j] * sA[i];
                float V[16];
                compute_V(&sW[((i>>4)*5 + j)*16], &sM[i*16], V);
                V[0] += (float)((i & 15) >> 2) * 0.25f;
                V[1] += (float)(i & 3) * 0.25f;
                wr[u] = wgt; cw += wgt;
                #pragma unroll
                for (int m = 0; m < 16; ++m) { Vr[u][m] = V[m]; cm[m] = fmaf(wgt, V[m], cm[m]); }
            }
            for (int off = 1; off < 64; off <<= 1) {
                cw += __shfl_xor(cw, off);
                #pragma unroll
                for (int m = 0; m < 16; ++m) cm[m] += __shfl_xor(cm[m], off);
            }
            if (lane == 0) { red[wave][0] = cw; for (int m = 0; m < 16; ++m) red[wave][1+m] = cm[m]; }
            __syncthreads();
            float coeff = fmaxf(red[0][0]+red[1][0]+red[2][0]+red[3][0], 1e-8f);
            float mu[16];
            #pragma unroll
            for (int m = 0; m < 16; ++m)
                mu[m] = (red[0][1+m]+red[1][1+m]+red[2][1+m]+red[3][1+m]) / coeff;
            __syncthreads();
            float cs[16];
            #pragma unroll
            for (int m = 0; m < 16; ++m) cs[m] = 0.f;
            #pragma unroll
            for (int u = 0; u < 2; ++u)
                #pragma unroll
                for (int m = 0; m < 16; ++m) {
                    float d = Vr[u][m] - mu[m];
                    cs[m] = fmaf(wr[u], d*d, cs[m]);
                }
            for (int off = 1; off < 64; off <<= 1) {
                #pragma unroll
                for (int m = 0; m < 16; ++m) cs[m] += __shfl_xor(cs[m], off);
            }
            if (lane == 0) for (int m = 0; m < 16; ++m) red[wave][m] = cs[m];
            __syncthreads();
            float lsum = 0.f, isv[16];
            #pragma unroll
            for (int m = 0; m < 16; ++m) {
                float s = fmaxf((red[0][m]+red[1][m]+red[2][m]+red[3][m]) / coeff, 1e-8f);
                lsum += logf(s);
                isv[m] = 1.f / s;
            }
            float ao = 1.f/(1.f + expf(-(lam * (ba4[j] - (16.f*bu4[j] + 0.5f*lsum) * coeff))));
            if (tid == 0) {
                for (int m = 0; m < 16; ++m) { sStat[j][m] = mu[m]; sStat[j][16+m] = isv[m]; }
                sStat[j][32] = lsum; sStat[j][33] = ao;
            }
            __syncthreads();
        }
        if (t < 2) {
            #pragma unroll
            for (int u = 0; u < 2; ++u) {
                int i = tid + u*256;
                float sv[5], mxv = -3.0e38f;
                #pragma unroll
                for (int j = 0; j < 5; ++j) {
                    float V[16];
                    compute_V(&sW[((i>>4)*5 + j)*16], &sM[i*16], V);
                    V[0] += (float)((i & 15) >> 2) * 0.25f;
                    V[1] += (float)(i & 3) * 0.25f;
                    float q = 0.f;
                    #pragma unroll
                    for (int m = 0; m < 16; ++m) {
                        float d = V[m] - sStat[j][m];
                        q = fmaf(d*d, sStat[j][16+m], q);
                    }
                    float logp = -0.5f * (16.f*LN2PI + sStat[j][32] + q);
                    sv[j] = sStat[j][33] * logp;
                    mxv = fmaxf(mxv, sv[j]);
                }
                float sum = 0.f;
                #pragma unroll
                for (int j = 0; j < 5; ++j) { sv[j] = expf(sv[j] - mxv); sum += sv[j]; }
                float inv = 1.f / sum;
                #pragma unroll
                for (int j = 0; j < 5; ++j) sR[i*5 + j] = sv[j] * inv;
            }
            __syncthreads();
        }
    }
    if (tid < 5) out[b*5 + tid] = sStat[tid][33];
}

// ---------------------------------------------------------------------------
// host: one EM layer (layers 2/3)
// ---------------------------------------------------------------------------
template<int NI, int NJ, int P, int C>
static void run_em(hipStream_t stream,
                   const float* aP, const float* Mp, const float* W, const float* Wt,
                   const float* ba, const float* bu,
                   float* mxs, float* ismb,
                   float* miu, float* isg, float* lssb, float* ao,
                   float* a_fin, float* M_fin)
{
    const float lams[3] = {5.0e-4f, 9.75e-4f, 1.426250e-3f};
    for (int t = 0; t < 3; ++t) {
        k_stats<NI,NJ,P,C><<<16*NJ, 64, 0, stream>>>(
            aP, Mp, Wt, mxs, ismb, ba, bu, miu, isg, lssb, ao, a_fin, M_fin,
            t, lams[t], (t == 2) ? 1 : 0);
        if (t < 2) {
            k_Rred<NI,NJ,P,C><<<16*(NI/4), 256, 0, stream>>>(
                Mp, W, miu, isg, lssb, ao, mxs, ismb);
        }
    }
}

extern "C" void kernel_launch(void* const* d_in, const int* in_sizes, int n_in,
                              void* d_out, int out_size, void* d_ws, size_t ws_size,
                              hipStream_t stream) {
    (void)in_sizes; (void)n_in; (void)out_size; (void)ws_size;
    const float* x       = (const float*)d_in[0];
    const float* conv_w  = (const float*)d_in[1];
    const float* conv_b  = (const float*)d_in[2];
    const float* pose_w  = (const float*)d_in[3];
    const float* pose_b  = (const float*)d_in[4];
    const float* act_w   = (const float*)d_in[5];
    const float* act_b   = (const float*)d_in[6];
    const float* W2      = (const float*)d_in[7];
    const float* beta_a2 = (const float*)d_in[8];
    const float* beta_u2 = (const float*)d_in[9];
    const float* W3      = (const float*)d_in[10];
    const float* beta_a3 = (const float*)d_in[11];
    const float* beta_u3 = (const float*)d_in[12];
    const float* W4      = (const float*)d_in[13];
    const float* beta_a4 = (const float*)d_in[14];
    const float* beta_u4 = (const float*)d_in[15];

    // workspace layout (floats), total ~5.9M floats = 23.4 MB
    float* ws   = (float*)d_ws;
    float* fea  = ws;                    // 100352
    float* a1   = fea  + 100352;         // 100352
    float* M1   = a1   + 100352;         // 1605632
    float* aP   = M1   + 1605632;        // 165888 (max)
    float* Mp   = aP   + 165888;         // 2654208 (max)
    float* Wt   = Mp   + 2654208;        // 147456
    float* miu  = Wt   + 147456;         // 294912 (max 16*1152*16)
    float* isg  = miu  + 294912;         // 294912
    float* lssb = isg  + 294912;         // 18432
    float* ao   = lssb + 18432;          // 18432
    float* mxs  = ao   + 18432;          // 4608
    float* ismb = mxs  + 4608;           // 4608
    float* a2   = ismb + 4608;           // 18432
    float* M2   = a2   + 18432;          // 294912
    float* a3   = M2   + 294912;         // 8192
    float* M3   = a3   + 8192;           // 131072

    // stem + primary caps
    k_stem<<<(16*32*196 + 255)/256, 256, 0, stream>>>(x, conv_w, conv_b, fea);
    k_primary<<<(16*544*196 + 255)/256, 256, 0, stream>>>(fea, pose_w, pose_b,
                                                          act_w, act_b, M1, a1);

    // layer 2: B=32,C=32,K=3,s=2, 14x14 -> 6x6 ; NI=288, NJ=1152, P=36
    k_patch<<<(16*288*36 + 255)/256, 256, 0, stream>>>(a1, M1, aP, Mp, 32, 3, 2, 14, 14, 6, 6);
    k_wt<<<(288*32*16 + 255)/256, 256, 0, stream>>>(W2, Wt, 288, 32);
    run_em<288,1152,36,32>(stream, aP, Mp, W2, Wt, beta_a2, beta_u2,
                           mxs, ismb, miu, isg, lssb, ao, a2, M2);

    // layer 3: B=32,C=32,K=3,s=1, 6x6 -> 4x4 ; NI=288, NJ=512, P=16
    k_patch<<<(16*288*16 + 255)/256, 256, 0, stream>>>(a2, M2, aP, Mp, 32, 3, 1, 6, 6, 4, 4);
    k_wt<<<(288*32*16 + 255)/256, 256, 0, stream>>>(W3, Wt, 288, 32);
    run_em<288,512,16,32>(stream, aP, Mp, W3, Wt, beta_a3, beta_u3,
                          mxs, ismb, miu, isg, lssb, ao, a3, M3);

    // layer 4 fused: B=32,C=5,K=4,s=1, 4x4 -> 1x1, share+coord
    k_layer4<<<16, 256, 0, stream>>>(a3, M3, W4, beta_a4, beta_u4, (float*)d_out);
}